// Round 8
// baseline (174.590 us; speedup 1.0000x reference)
//
#include <hip/hip_runtime.h>
#include <float.h>

#define DEVI __device__ __forceinline__

namespace {

constexpr int NB   = 8;     // batch
constexpr int CD   = 256;   // dense channels
constexpr int CS   = 512;   // sparse channels
constexpr int MM   = 4096;  // dense points
constexpr int SS   = 1024;  // sparse points
constexpr int NN   = 4096;  // pcd points
constexpr int KTOT = 768;   // CD + CS
constexpr int OC   = 256;   // output channels
constexpr float KEPS  = 1e-8f;
constexpr float BNEPS = 1e-5f;
constexpr float SLOPE = 0.2f;

// ---------------- workspace layout (bytes) — total ~10.6 MB (verified fit) ----------------
constexpr size_t OFF_Z    = 0;                              // float [NB][SS][OC]  Z = W_s * sparse
constexpr size_t SZ_Z     = (size_t)NB * SS * OC * 4;       // 8,388,608
constexpr size_t OFF_IDX3 = OFF_Z + SZ_Z;                   // int   [NB][MM][3]
constexpr size_t SZ_IDX3  = (size_t)NB * MM * 3 * 4;        // 393,216
constexpr size_t OFF_W3   = OFF_IDX3 + SZ_IDX3;             // float [NB][MM][3]
constexpr size_t OFF_WBF  = OFF_W3 + SZ_IDX3;               // bf16  [OC][KTOT]
constexpr size_t SZ_WBF   = (size_t)OC * KTOT * 2;          // 393,216
constexpr size_t OFF_PS   = OFF_WBF + SZ_WBF;               // float [512][OC] partial sums
constexpr size_t SZ_PS    = (size_t)512 * OC * 4;           // 524,288
constexpr size_t OFF_PS2  = OFF_PS + SZ_PS;                 // float [512][OC] partial sumsq
constexpr size_t OFF_A    = OFF_PS2 + SZ_PS;                // float [OC]  scale = rs*gamma
constexpr size_t OFF_B    = OFF_A + 1024;                   // float [OC]  shift = beta - mu*scale

typedef __attribute__((ext_vector_type(8))) short s16x8;
typedef __attribute__((ext_vector_type(4))) float f32x4;

// float -> bf16 (RNE), returned as raw short
DEVI short f2bf(float f) {
  union { float f; unsigned u; } c; c.f = f;
  unsigned r = c.u + 0x7fffu + ((c.u >> 16) & 1u);
  return (short)(r >> 16);
}

DEVI unsigned umin_(unsigned a, unsigned b) { return a < b ? a : b; }
DEVI unsigned umax_(unsigned a, unsigned b) { return a > b ? a : b; }

// ---------------------------------------------------------------- KNN top-3 (+ conv_w cast prologue)
// Packed-key top-3: key = (bits(d) & ~1023) | candidate_idx.  d >= 0 so uint order == float
// order; low 10 mantissa bits carry the index (ties -> lower index, matching top_k).
// Insertion = 5 unsigned min/max, no vcc chains.
__global__ __launch_bounds__(256) void k_knn(
    const int* __restrict__ didx, const int* __restrict__ sidx,
    const float* __restrict__ pcd,
    int* __restrict__ idx3, float* __restrict__ w3,
    float* __restrict__ outIdxF,
    const float* __restrict__ convw, short* __restrict__ wbf) {
  __shared__ float4   sxyz[SS];            // 16 KB candidate coords (+|s|^2 in .w)
  __shared__ unsigned pk[4][64][3];        // partial top-3 packed keys

  int blk = blockIdx.x;                    // 8 * 64 = 512 blocks
  int b   = blk >> 6;
  int m0  = (blk & 63) << 6;
  int tid = threadIdx.x;
  const float* pb = pcd + (size_t)b * 3 * NN;

  // folded k_wcast: 512 blocks * 384 = 196608 = OC*KTOT exactly
  for (int i = tid; i < 384; i += 256) {
    int g = blk * 384 + i;
    wbf[g] = f2bf(convw[g]);
  }

  for (int s = tid; s < SS; s += 256) {
    int si = sidx[b * SS + s];
    float x = pb[si], yy = pb[NN + si], z = pb[2 * NN + si];
    sxyz[s] = make_float4(x, yy, z, x * x + yy * yy + z * z);
  }

  int p     = tid & 63;                    // point within tile
  int chunk = tid >> 6;                    // candidate chunk
  int m     = m0 + p;
  int di    = didx[b * MM + m];
  float px = pb[di], py = pb[NN + di], pz = pb[2 * NN + di];
  float pp = px * px + py * py + pz * pz;
  float nx = -2.f * px, ny = -2.f * py, nz = -2.f * pz;

  if (chunk == 0) outIdxF[b * MM + m] = (float)di;   // output 1

  __syncthreads();

  unsigned k0 = 0xFFFFFFFFu, k1 = 0xFFFFFFFFu, k2 = 0xFFFFFFFFu;
  int s0c = chunk << 8;
#pragma unroll 4
  for (int t = 0; t < 256; ++t) {
    int s = s0c + t;
    float4 c = sxyz[s];
    float d = fmaf(nx, c.x, c.w + pp);
    d = fmaf(ny, c.y, d);
    d = fmaf(nz, c.z, d);
    d = fmaxf(d, 0.f);                     // |p-s|^2 >= 0 (guard cancellation)
    unsigned key = (__float_as_uint(d) & 0xFFFFFC00u) | (unsigned)s;
    unsigned e0 = umax_(key, k0); k0 = umin_(key, k0);
    unsigned e1 = umax_(e0, k1);  k1 = umin_(e0, k1);
    k2 = umin_(e1, k2);
  }
  pk[chunk][p][0] = k0; pk[chunk][p][1] = k1; pk[chunk][p][2] = k2;
  __syncthreads();

  if (tid < 64) {
    unsigned g0 = 0xFFFFFFFFu, g1 = 0xFFFFFFFFu, g2 = 0xFFFFFFFFu;
#pragma unroll
    for (int c = 0; c < 4; ++c)
#pragma unroll
      for (int r = 0; r < 3; ++r) {
        unsigned key = pk[c][p][r];
        unsigned e0 = umax_(key, g0); g0 = umin_(key, g0);
        unsigned e1 = umax_(e0, g1);  g1 = umin_(e0, g1);
        g2 = umin_(e1, g2);
      }
    int j0 = g0 & 1023, j1 = g1 & 1023, j2 = g2 & 1023;
    float e0 = __uint_as_float(g0 & 0xFFFFFC00u);
    float e1 = __uint_as_float(g1 & 0xFFFFFC00u);
    float e2 = __uint_as_float(g2 & 0xFFFFFC00u);
    float w0 = 1.f / (e0 + KEPS), w1 = 1.f / (e1 + KEPS), w2 = 1.f / (e2 + KEPS);
    float inv = 1.f / (w0 + w1 + w2);
    int base = (b * MM + m) * 3;
    idx3[base] = j0; idx3[base + 1] = j1; idx3[base + 2] = j2;
    w3[base] = w0 * inv; w3[base + 1] = w1 * inv; w3[base + 2] = w2 * inv;
  }
}

// ---------------------------------------------------------------- Z = W_s * sparse
// Z[b][s][o] = sum_c W[o][CD+c] * sp[b][c][s].  Tile: 32 s x 256 o, BK=64.
__global__ __launch_bounds__(256) void k_gemmZ(
    const float* __restrict__ sp, const short* __restrict__ wbf,
    float* __restrict__ Z) {
  __shared__ __align__(16) short Wl[256 * 72];   // [o][k] pad 64->72 (144B rows)
  __shared__ __align__(16) short Sl[32 * 72];    // [s][k] pad 64->72

  int blk = blockIdx.x;                 // 8 * 32 = 256 blocks
  int st = blk & 31, b = blk >> 5;
  int s0 = st * 32;
  int tid = threadIdx.x, wv = tid >> 6, lane = tid & 63;
  int lo = lane & 15, quad = lane >> 4;

  f32x4 acc[4][2] = {};
  for (int k0 = 0; k0 < CS; k0 += 64) {
    __syncthreads();
    // stage W_s slice [256][64] bf16 via b128
#pragma unroll
    for (int r = 0; r < 8; ++r) {
      int lin = r * 256 + tid, row = lin >> 3, c8 = lin & 7;
      uint4 v = *(const uint4*)((const unsigned short*)wbf + (size_t)row * KTOT + CD + k0 + c8 * 8);
      *(uint4*)(&Wl[row * 72 + c8 * 8]) = v;
    }
    // stage sp slice [64 c][32 s] -> Sl[s][c] (inline transpose + f32->bf16)
#pragma unroll
    for (int r = 0; r < 2; ++r) {
      int lin = r * 256 + tid, cc = lin >> 3, s4 = lin & 7;
      float4 v = *(const float4*)(sp + (size_t)(b * CS + k0 + cc) * SS + s0 + s4 * 4);
      Sl[(s4 * 4 + 0) * 72 + cc] = f2bf(v.x);
      Sl[(s4 * 4 + 1) * 72 + cc] = f2bf(v.y);
      Sl[(s4 * 4 + 2) * 72 + cc] = f2bf(v.z);
      Sl[(s4 * 4 + 3) * 72 + cc] = f2bf(v.w);
    }
    __syncthreads();
    s16x8 af[2][4], bfr[2][2];
#pragma unroll
    for (int h = 0; h < 2; ++h) {
#pragma unroll
      for (int i = 0; i < 4; ++i)
        af[h][i] = *(const s16x8*)(&Wl[(wv * 64 + i * 16 + lo) * 72 + h * 32 + quad * 8]);
#pragma unroll
      for (int j = 0; j < 2; ++j)
        bfr[h][j] = *(const s16x8*)(&Sl[(j * 16 + lo) * 72 + h * 32 + quad * 8]);
    }
#pragma unroll
    for (int h = 0; h < 2; ++h)
#pragma unroll
      for (int i = 0; i < 4; ++i)
#pragma unroll
        for (int j = 0; j < 2; ++j)
          acc[i][j] = __builtin_amdgcn_mfma_f32_16x16x32_bf16(af[h][i], bfr[h][j], acc[i][j], 0, 0, 0);
  }
  // write Z[b][s][o] — lane's 4 regs are 4 consecutive o -> float4 store
#pragma unroll
  for (int i = 0; i < 4; ++i)
#pragma unroll
    for (int j = 0; j < 2; ++j) {
      int s = j * 16 + lo, o = wv * 64 + i * 16 + quad * 4;
      *(f32x4*)(Z + (size_t)(b * SS + s0 + s) * OC + o) = acc[i][j];
    }
}

// ---------------------------------------------------------------- dense GEMM + combine + stats
// y[b][o][m] (f32, raw pre-BN) = sum_k W[o][k]*dense_bf[b][k][m]
//                              + sum_j w3[m][j]*Z[b][idx3[m][j]][o]
// Tile: 64 m x 128 o (o split 2x for occupancy: LDS 28.5 KB -> 5 blocks/CU co-resident).
// 4 waves each 32o x 64m. K=256, BK=64 -> 4 steps.
// Stats partials: ps row = (b,mt) — the two ot-blocks write disjoint column halves, so
// values and summation order are bit-identical to the 256o-tile version.
__global__ __launch_bounds__(256) void k_gemmDC(
    const float* __restrict__ dense, const float* __restrict__ Z,
    const int* __restrict__ idx3, const float* __restrict__ w3,
    const short* __restrict__ wbf, float* __restrict__ y,
    float* __restrict__ ps, float* __restrict__ ps2) {
  __shared__ __align__(16) short Wl[128 * 72];   // [o_local][k] pad 64->72; reused as P[32][132] f32
  __shared__ __align__(16) short Xl[64 * 72];    // [m][k] pad 64->72
  __shared__ int   mi3[192];
  __shared__ float mw3[192];

  int blk = blockIdx.x;                 // 8 * 2 * 64 = 1024 blocks
  int mt = blk & 63, ot = (blk >> 6) & 1, b = blk >> 7;
  int m0 = mt << 6, o0 = ot << 7;
  int tid = threadIdx.x, wv = tid >> 6, lane = tid & 63;
  int lo = lane & 15, quad = lane >> 4;
  int wo = wv << 5;                     // wave's 32-o slice within the 128-o tile

  {
    int base = (b * MM + m0) * 3;
    for (int i = tid; i < 192; i += 256) { mi3[i] = idx3[base + i]; mw3[i] = w3[base + i]; }
  }

  f32x4 acc[2][4] = {};
  for (int k0 = 0; k0 < CD; k0 += 64) {
    __syncthreads();
    // stage W_d slice [128][64] bf16 (rows o0..o0+127)
#pragma unroll
    for (int r = 0; r < 4; ++r) {
      int lin = r * 256 + tid, row = lin >> 3, c8 = lin & 7;
      uint4 v = *(const uint4*)((const unsigned short*)wbf + (size_t)(o0 + row) * KTOT + k0 + c8 * 8);
      *(uint4*)(&Wl[row * 72 + c8 * 8]) = v;
    }
    // stage dense slice [64 k][64 m] -> Xl[m][k]: each thread loads 4 float4 along k,
    // packs ushort4 per m-row -> 4x ds_write_b64
    {
      int kk4 = tid >> 4, m4 = tid & 15;          // k-quad, m-quad
      float4 v0 = *(const float4*)(dense + (size_t)(b * CD + k0 + kk4 * 4 + 0) * MM + m0 + m4 * 4);
      float4 v1 = *(const float4*)(dense + (size_t)(b * CD + k0 + kk4 * 4 + 1) * MM + m0 + m4 * 4);
      float4 v2 = *(const float4*)(dense + (size_t)(b * CD + k0 + kk4 * 4 + 2) * MM + m0 + m4 * 4);
      float4 v3 = *(const float4*)(dense + (size_t)(b * CD + k0 + kk4 * 4 + 3) * MM + m0 + m4 * 4);
      ushort4 w;
      w.x = (unsigned short)f2bf(v0.x); w.y = (unsigned short)f2bf(v1.x);
      w.z = (unsigned short)f2bf(v2.x); w.w = (unsigned short)f2bf(v3.x);
      *(ushort4*)(&Xl[(m4 * 4 + 0) * 72 + kk4 * 4]) = w;
      w.x = (unsigned short)f2bf(v0.y); w.y = (unsigned short)f2bf(v1.y);
      w.z = (unsigned short)f2bf(v2.y); w.w = (unsigned short)f2bf(v3.y);
      *(ushort4*)(&Xl[(m4 * 4 + 1) * 72 + kk4 * 4]) = w;
      w.x = (unsigned short)f2bf(v0.z); w.y = (unsigned short)f2bf(v1.z);
      w.z = (unsigned short)f2bf(v2.z); w.w = (unsigned short)f2bf(v3.z);
      *(ushort4*)(&Xl[(m4 * 4 + 2) * 72 + kk4 * 4]) = w;
      w.x = (unsigned short)f2bf(v0.w); w.y = (unsigned short)f2bf(v1.w);
      w.z = (unsigned short)f2bf(v2.w); w.w = (unsigned short)f2bf(v3.w);
      *(ushort4*)(&Xl[(m4 * 4 + 3) * 72 + kk4 * 4]) = w;
    }
    __syncthreads();
    s16x8 af[2][2], bfr[2][4];
#pragma unroll
    for (int h = 0; h < 2; ++h) {
#pragma unroll
      for (int i = 0; i < 2; ++i)
        af[h][i] = *(const s16x8*)(&Wl[(wo + i * 16 + lo) * 72 + h * 32 + quad * 8]);
#pragma unroll
      for (int j = 0; j < 4; ++j)
        bfr[h][j] = *(const s16x8*)(&Xl[(j * 16 + lo) * 72 + h * 32 + quad * 8]);
    }
#pragma unroll
    for (int h = 0; h < 2; ++h)
#pragma unroll
      for (int i = 0; i < 2; ++i)
#pragma unroll
        for (int j = 0; j < 4; ++j)
          acc[i][j] = __builtin_amdgcn_mfma_f32_16x16x32_bf16(af[h][i], bfr[h][j], acc[i][j], 0, 0, 0);
  }

  // ---------------- epilogue: combine with interp projection, store raw f32, stats
  float* P = (float*)Wl;                 // [32][132] f32, pad 128->132 (16.9 KB <= 18.4 KB)
  const float* Zb = Z + (size_t)b * SS * OC;
  float ss[2][4] = {}, s2s[2][4] = {};
  __syncthreads();                       // Wl MFMA reads done, safe to reuse as P

#pragma unroll
  for (int h = 0; h < 2; ++h) {
    // build P[ml][ol] = sum_j w_j * Z[idx_j][o0+ol] for m-half h (coalesced row reads)
#pragma unroll 4
    for (int t = 0; t < 16; ++t) {
      int idx = t * 256 + tid;
      int ml = idx >> 7, ol = idx & 127;
      int mg = (h * 32 + ml) * 3;
      float p = mw3[mg + 0] * Zb[(size_t)mi3[mg + 0] * OC + o0 + ol]
              + mw3[mg + 1] * Zb[(size_t)mi3[mg + 1] * OC + o0 + ol]
              + mw3[mg + 2] * Zb[(size_t)mi3[mg + 2] * OC + o0 + ol];
      P[ml * 132 + ol] = p;
    }
    __syncthreads();
#pragma unroll
    for (int i = 0; i < 2; ++i)
#pragma unroll
      for (int jj = 0; jj < 2; ++jj) {
        int j = h * 2 + jj, ml = jj * 16 + lo;
        int ol = wo + i * 16 + quad * 4;
        f32x4 p = *(const f32x4*)(&P[ml * 132 + ol]);
        f32x4 v = acc[i][j] + p;
        float* dst = y + (size_t)(b * OC + o0 + ol) * MM + m0 + j * 16 + lo;
#pragma unroll
        for (int r = 0; r < 4; ++r) {
          float vv = v[r];
          dst[(size_t)r * MM] = vv;
          ss[i][r] += vv; s2s[i][r] += vv * vv;
        }
      }
    __syncthreads();
  }

  // reduce stats across the 16 m-lanes of each quad (deterministic), write partials
#pragma unroll
  for (int i = 0; i < 2; ++i)
#pragma unroll
    for (int r = 0; r < 4; ++r) {
      float a = ss[i][r], q = s2s[i][r];
      for (int off = 1; off < 16; off <<= 1) { a += __shfl_xor(a, off); q += __shfl_xor(q, off); }
      ss[i][r] = a; s2s[i][r] = q;
    }
  if (lo == 0) {
    int psRow = b * 64 + mt;             // same 512 rows as before; ot-blocks fill disjoint cols
#pragma unroll
    for (int i = 0; i < 2; ++i)
#pragma unroll
      for (int r = 0; r < 4; ++r) {
        int o = o0 + wo + i * 16 + quad * 4 + r;
        ps[(size_t)psRow * OC + o]  = ss[i][r];
        ps2[(size_t)psRow * OC + o] = s2s[i][r];
      }
  }
}

// ---------------------------------------------------------------- BN finalize -> fused scale/shift
// parallelized: 8 blocks x 32 channels (was 1 block idling the GPU)
__global__ void k_finalize(const float* __restrict__ ps, const float* __restrict__ ps2,
                           const float* __restrict__ gamma, const float* __restrict__ beta,
                           float* __restrict__ sA, float* __restrict__ sB) {
  __shared__ float red[512];
  int blk = blockIdx.x;                    // 8 blocks
  int tid = threadIdx.x;
  int ch = tid & 31, sl = tid >> 5;        // 32 channels x 8 k-slices
  int o = blk * 32 + ch;
  float s = 0.f, s2 = 0.f;
#pragma unroll 4
  for (int j = 0; j < 64; ++j) {
    int k = sl * 64 + j;
    s  += ps[(size_t)k * OC + o];
    s2 += ps2[(size_t)k * OC + o];
  }
  red[sl * 32 + ch] = s;
  red[256 + sl * 32 + ch] = s2;
  __syncthreads();
  if (tid < 32) {
    float S = 0.f, S2 = 0.f;
#pragma unroll
    for (int t = 0; t < 8; ++t) { S += red[t * 32 + tid]; S2 += red[256 + t * 32 + tid]; }
    int oo = blk * 32 + tid;
    float mn = S / (float)(NB * MM);
    float vr = S2 / (float)(NB * MM) - mn * mn;
    float a  = rsqrtf(vr + BNEPS) * gamma[oo];
    sA[oo] = a;
    sB[oo] = beta[oo] - mn * a;
  }
}

// ---------------------------------------------------------------- BN apply + LeakyReLU (in place)
__global__ void k_norm(float* __restrict__ y, const float* __restrict__ sA,
                       const float* __restrict__ sB) {
  int i = blockIdx.x * 256 + threadIdx.x;   // float4 index; grid covers exactly
  int o = (i >> 10) & 255;                  // 1024 float4 per (b,o) row
  float a = sA[o], be = sB[o];
  float4 v = ((const float4*)y)[i];
  float t;
  t = v.x * a + be; v.x = t >= 0.f ? t : SLOPE * t;
  t = v.y * a + be; v.y = t >= 0.f ? t : SLOPE * t;
  t = v.z * a + be; v.z = t >= 0.f ? t : SLOPE * t;
  t = v.w * a + be; v.w = t >= 0.f ? t : SLOPE * t;
  ((float4*)y)[i] = v;
}

}  // namespace

extern "C" void kernel_launch(void* const* d_in, const int* in_sizes, int n_in,
                              void* d_out, int out_size, void* d_ws, size_t ws_size,
                              hipStream_t stream) {
  const float* dense = (const float*)d_in[0];
  const int*   didx  = (const int*)d_in[1];
  const float* sp    = (const float*)d_in[2];
  const int*   sidx  = (const int*)d_in[3];
  const float* pcd   = (const float*)d_in[4];
  const float* convw = (const float*)d_in[5];
  const float* gamma = (const float*)d_in[6];
  const float* beta  = (const float*)d_in[7];

  float* y = (float*)d_out;                       // [8][256][4096] raw -> normalized in place
  float* outIdxF = y + (size_t)NB * OC * MM;      // output 1: dense_idx as float

  char* ws = (char*)d_ws;                         // needs ~10.6 MB
  float* Z    = (float*)(ws + OFF_Z);
  int*   idx3 = (int*)(ws + OFF_IDX3);
  float* w3   = (float*)(ws + OFF_W3);
  short* wbf  = (short*)(ws + OFF_WBF);
  float* ps   = (float*)(ws + OFF_PS);
  float* ps2  = (float*)(ws + OFF_PS2);
  float* sA   = (float*)(ws + OFF_A);
  float* sB   = (float*)(ws + OFF_B);

  k_knn     <<<NB * (MM / 64), 256, 0, stream>>>(didx, sidx, pcd, idx3, w3, outIdxF, convw, wbf);
  k_gemmZ   <<<NB * (SS / 32), 256, 0, stream>>>(sp, wbf, Z);
  k_gemmDC  <<<NB * 2 * (MM / 64), 256, 0, stream>>>(dense, Z, idx3, w3, wbf, y, ps, ps2);
  k_finalize<<<8, 256, 0, stream>>>(ps, ps2, gamma, beta, sA, sB);
  k_norm    <<<(NB * OC * MM / 4) / 256, 256, 0, stream>>>(y, sA, sB);
}

// Round 9
// 163.317 us; speedup vs baseline: 1.0690x; 1.0690x over previous
//
#include <hip/hip_runtime.h>
#include <float.h>

#define DEVI __device__ __forceinline__

namespace {

constexpr int NB   = 8;     // batch
constexpr int CD   = 256;   // dense channels
constexpr int CS   = 512;   // sparse channels
constexpr int MM   = 4096;  // dense points
constexpr int SS   = 1024;  // sparse points
constexpr int NN   = 4096;  // pcd points
constexpr int KTOT = 768;   // CD + CS
constexpr int OC   = 256;   // output channels
constexpr float KEPS  = 1e-8f;
constexpr float BNEPS = 1e-5f;
constexpr float SLOPE = 0.2f;

// ---------------- workspace layout (bytes) — total ~27.4 MB (ws = 256 MiB, verified via fill counter) ----
constexpr size_t OFF_Z    = 0;                              // float [NB][SS][OC]  Z = W_s * sparse
constexpr size_t SZ_Z     = (size_t)NB * SS * OC * 4;       // 8,388,608
constexpr size_t OFF_RAW  = OFF_Z + SZ_Z;                   // bf16  [NB][OC][MM] raw pre-BN y
constexpr size_t SZ_RAW   = (size_t)NB * OC * MM * 2;       // 16,777,216
constexpr size_t OFF_IDX3 = OFF_RAW + SZ_RAW;               // int   [NB][MM][3]
constexpr size_t SZ_IDX3  = (size_t)NB * MM * 3 * 4;        // 393,216
constexpr size_t OFF_W3   = OFF_IDX3 + SZ_IDX3;             // float [NB][MM][3]
constexpr size_t OFF_WBF  = OFF_W3 + SZ_IDX3;               // bf16  [OC][KTOT]
constexpr size_t SZ_WBF   = (size_t)OC * KTOT * 2;          // 393,216
constexpr size_t OFF_PS   = OFF_WBF + SZ_WBF;               // float [512][OC] partial sums
constexpr size_t SZ_PS    = (size_t)512 * OC * 4;           // 524,288
constexpr size_t OFF_PS2  = OFF_PS + SZ_PS;                 // float [512][OC] partial sumsq
constexpr size_t OFF_A    = OFF_PS2 + SZ_PS;                // float [OC]  scale = rs*gamma
constexpr size_t OFF_B    = OFF_A + 1024;                   // float [OC]  shift = beta - mu*scale

typedef __attribute__((ext_vector_type(8))) short s16x8;
typedef __attribute__((ext_vector_type(8))) unsigned short u16x8;
typedef __attribute__((ext_vector_type(4))) float f32x4;

// float -> bf16 (RNE), returned as raw short
DEVI short f2bf(float f) {
  union { float f; unsigned u; } c; c.f = f;
  unsigned r = c.u + 0x7fffu + ((c.u >> 16) & 1u);
  return (short)(r >> 16);
}

DEVI unsigned umin_(unsigned a, unsigned b) { return a < b ? a : b; }
DEVI unsigned umax_(unsigned a, unsigned b) { return a > b ? a : b; }

// ---------------------------------------------------------------- KNN top-3 (+ conv_w cast prologue)
// Packed-key top-3: key = (bits(d) & ~1023) | candidate_idx.  d >= 0 so uint order == float
// order; low 10 mantissa bits carry the index (ties -> lower index, matching top_k).
// Insertion = 5 unsigned min/max, no vcc chains.
__global__ __launch_bounds__(256) void k_knn(
    const int* __restrict__ didx, const int* __restrict__ sidx,
    const float* __restrict__ pcd,
    int* __restrict__ idx3, float* __restrict__ w3,
    float* __restrict__ outIdxF,
    const float* __restrict__ convw, short* __restrict__ wbf) {
  __shared__ float4   sxyz[SS];            // 16 KB candidate coords (+|s|^2 in .w)
  __shared__ unsigned pk[4][64][3];        // partial top-3 packed keys

  int blk = blockIdx.x;                    // 8 * 64 = 512 blocks
  int b   = blk >> 6;
  int m0  = (blk & 63) << 6;
  int tid = threadIdx.x;
  const float* pb = pcd + (size_t)b * 3 * NN;

  // folded k_wcast: 512 blocks * 384 = 196608 = OC*KTOT exactly
  for (int i = tid; i < 384; i += 256) {
    int g = blk * 384 + i;
    wbf[g] = f2bf(convw[g]);
  }

  for (int s = tid; s < SS; s += 256) {
    int si = sidx[b * SS + s];
    float x = pb[si], yy = pb[NN + si], z = pb[2 * NN + si];
    sxyz[s] = make_float4(x, yy, z, x * x + yy * yy + z * z);
  }

  int p     = tid & 63;                    // point within tile
  int chunk = tid >> 6;                    // candidate chunk
  int m     = m0 + p;
  int di    = didx[b * MM + m];
  float px = pb[di], py = pb[NN + di], pz = pb[2 * NN + di];
  float pp = px * px + py * py + pz * pz;
  float nx = -2.f * px, ny = -2.f * py, nz = -2.f * pz;

  if (chunk == 0) outIdxF[b * MM + m] = (float)di;   // output 1

  __syncthreads();

  unsigned k0 = 0xFFFFFFFFu, k1 = 0xFFFFFFFFu, k2 = 0xFFFFFFFFu;
  int s0c = chunk << 8;
#pragma unroll 4
  for (int t = 0; t < 256; ++t) {
    int s = s0c + t;
    float4 c = sxyz[s];
    float d = fmaf(nx, c.x, c.w + pp);
    d = fmaf(ny, c.y, d);
    d = fmaf(nz, c.z, d);
    d = fmaxf(d, 0.f);                     // |p-s|^2 >= 0 (guard cancellation)
    unsigned key = (__float_as_uint(d) & 0xFFFFFC00u) | (unsigned)s;
    unsigned e0 = umax_(key, k0); k0 = umin_(key, k0);
    unsigned e1 = umax_(e0, k1);  k1 = umin_(e0, k1);
    k2 = umin_(e1, k2);
  }
  pk[chunk][p][0] = k0; pk[chunk][p][1] = k1; pk[chunk][p][2] = k2;
  __syncthreads();

  if (tid < 64) {
    unsigned g0 = 0xFFFFFFFFu, g1 = 0xFFFFFFFFu, g2 = 0xFFFFFFFFu;
#pragma unroll
    for (int c = 0; c < 4; ++c)
#pragma unroll
      for (int r = 0; r < 3; ++r) {
        unsigned key = pk[c][p][r];
        unsigned e0 = umax_(key, g0); g0 = umin_(key, g0);
        unsigned e1 = umax_(e0, g1);  g1 = umin_(e0, g1);
        g2 = umin_(e1, g2);
      }
    int j0 = g0 & 1023, j1 = g1 & 1023, j2 = g2 & 1023;
    float e0 = __uint_as_float(g0 & 0xFFFFFC00u);
    float e1 = __uint_as_float(g1 & 0xFFFFFC00u);
    float e2 = __uint_as_float(g2 & 0xFFFFFC00u);
    float w0 = 1.f / (e0 + KEPS), w1 = 1.f / (e1 + KEPS), w2 = 1.f / (e2 + KEPS);
    float inv = 1.f / (w0 + w1 + w2);
    int base = (b * MM + m) * 3;
    idx3[base] = j0; idx3[base + 1] = j1; idx3[base + 2] = j2;
    w3[base] = w0 * inv; w3[base + 1] = w1 * inv; w3[base + 2] = w2 * inv;
  }
}

// ---------------------------------------------------------------- Z = W_s * sparse
// Z[b][s][o] = sum_c W[o][CD+c] * sp[b][c][s].  Tile: 32 s x 256 o, BK=64.
__global__ __launch_bounds__(256) void k_gemmZ(
    const float* __restrict__ sp, const short* __restrict__ wbf,
    float* __restrict__ Z) {
  __shared__ __align__(16) short Wl[256 * 72];   // [o][k] pad 64->72 (144B rows)
  __shared__ __align__(16) short Sl[32 * 72];    // [s][k] pad 64->72

  int blk = blockIdx.x;                 // 8 * 32 = 256 blocks
  int st = blk & 31, b = blk >> 5;
  int s0 = st * 32;
  int tid = threadIdx.x, wv = tid >> 6, lane = tid & 63;
  int lo = lane & 15, quad = lane >> 4;

  f32x4 acc[4][2] = {};
  for (int k0 = 0; k0 < CS; k0 += 64) {
    __syncthreads();
    // stage W_s slice [256][64] bf16 via b128
#pragma unroll
    for (int r = 0; r < 8; ++r) {
      int lin = r * 256 + tid, row = lin >> 3, c8 = lin & 7;
      uint4 v = *(const uint4*)((const unsigned short*)wbf + (size_t)row * KTOT + CD + k0 + c8 * 8);
      *(uint4*)(&Wl[row * 72 + c8 * 8]) = v;
    }
    // stage sp slice [64 c][32 s] -> Sl[s][c] (inline transpose + f32->bf16)
#pragma unroll
    for (int r = 0; r < 2; ++r) {
      int lin = r * 256 + tid, cc = lin >> 3, s4 = lin & 7;
      float4 v = *(const float4*)(sp + (size_t)(b * CS + k0 + cc) * SS + s0 + s4 * 4);
      Sl[(s4 * 4 + 0) * 72 + cc] = f2bf(v.x);
      Sl[(s4 * 4 + 1) * 72 + cc] = f2bf(v.y);
      Sl[(s4 * 4 + 2) * 72 + cc] = f2bf(v.z);
      Sl[(s4 * 4 + 3) * 72 + cc] = f2bf(v.w);
    }
    __syncthreads();
    s16x8 af[2][4], bfr[2][2];
#pragma unroll
    for (int h = 0; h < 2; ++h) {
#pragma unroll
      for (int i = 0; i < 4; ++i)
        af[h][i] = *(const s16x8*)(&Wl[(wv * 64 + i * 16 + lo) * 72 + h * 32 + quad * 8]);
#pragma unroll
      for (int j = 0; j < 2; ++j)
        bfr[h][j] = *(const s16x8*)(&Sl[(j * 16 + lo) * 72 + h * 32 + quad * 8]);
    }
#pragma unroll
    for (int h = 0; h < 2; ++h)
#pragma unroll
      for (int i = 0; i < 4; ++i)
#pragma unroll
        for (int j = 0; j < 2; ++j)
          acc[i][j] = __builtin_amdgcn_mfma_f32_16x16x32_bf16(af[h][i], bfr[h][j], acc[i][j], 0, 0, 0);
  }
  // write Z[b][s][o] — lane's 4 regs are 4 consecutive o -> float4 store
#pragma unroll
  for (int i = 0; i < 4; ++i)
#pragma unroll
    for (int j = 0; j < 2; ++j) {
      int s = j * 16 + lo, o = wv * 64 + i * 16 + quad * 4;
      *(f32x4*)(Z + (size_t)(b * SS + s0 + s) * OC + o) = acc[i][j];
    }
}

// ---------------------------------------------------------------- dense GEMM + combine + stats
// raw[b][o][m] (bf16) = sum_k W[o][k]*dense_bf[b][k][m] + sum_j w3[m][j]*Z[b][idx3[m][j]][o]
// Tile: 64 m x 256 o (full OC), 4 waves each 64o x 64m. K=256, BK=64 -> 4 steps.
// Stats accumulated from f32 values BEFORE bf16 quantization — bit-identical to the
// verified f32-raw version.
__global__ __launch_bounds__(256) void k_gemmDC(
    const float* __restrict__ dense, const float* __restrict__ Z,
    const int* __restrict__ idx3, const float* __restrict__ w3,
    const short* __restrict__ wbf, unsigned short* __restrict__ raw,
    float* __restrict__ ps, float* __restrict__ ps2) {
  __shared__ __align__(16) short Wl[256 * 72];   // [o][k] pad 64->72; reused as P[32][260] f32
  __shared__ __align__(16) short Xl[64 * 72];    // [m][k] pad 64->72
  __shared__ int   mi3[192];
  __shared__ float mw3[192];

  int blk = blockIdx.x;                 // 8 * 64 = 512 blocks
  int mt = blk & 63, b = blk >> 6, m0 = mt << 6;
  int tid = threadIdx.x, wv = tid >> 6, lane = tid & 63;
  int lo = lane & 15, quad = lane >> 4;

  {
    int base = (b * MM + m0) * 3;
    for (int i = tid; i < 192; i += 256) { mi3[i] = idx3[base + i]; mw3[i] = w3[base + i]; }
  }

  f32x4 acc[4][4] = {};
  for (int k0 = 0; k0 < CD; k0 += 64) {
    __syncthreads();
    // stage W_d slice [256][64] bf16
#pragma unroll
    for (int r = 0; r < 8; ++r) {
      int lin = r * 256 + tid, row = lin >> 3, c8 = lin & 7;
      uint4 v = *(const uint4*)((const unsigned short*)wbf + (size_t)row * KTOT + k0 + c8 * 8);
      *(uint4*)(&Wl[row * 72 + c8 * 8]) = v;
    }
    // stage dense slice [64 k][64 m] -> Xl[m][k]: each thread loads 4 float4 along k,
    // packs ushort4 per m-row -> 4x ds_write_b64
    {
      int kk4 = tid >> 4, m4 = tid & 15;          // k-quad, m-quad
      float4 v0 = *(const float4*)(dense + (size_t)(b * CD + k0 + kk4 * 4 + 0) * MM + m0 + m4 * 4);
      float4 v1 = *(const float4*)(dense + (size_t)(b * CD + k0 + kk4 * 4 + 1) * MM + m0 + m4 * 4);
      float4 v2 = *(const float4*)(dense + (size_t)(b * CD + k0 + kk4 * 4 + 2) * MM + m0 + m4 * 4);
      float4 v3 = *(const float4*)(dense + (size_t)(b * CD + k0 + kk4 * 4 + 3) * MM + m0 + m4 * 4);
      ushort4 w;
      w.x = (unsigned short)f2bf(v0.x); w.y = (unsigned short)f2bf(v1.x);
      w.z = (unsigned short)f2bf(v2.x); w.w = (unsigned short)f2bf(v3.x);
      *(ushort4*)(&Xl[(m4 * 4 + 0) * 72 + kk4 * 4]) = w;
      w.x = (unsigned short)f2bf(v0.y); w.y = (unsigned short)f2bf(v1.y);
      w.z = (unsigned short)f2bf(v2.y); w.w = (unsigned short)f2bf(v3.y);
      *(ushort4*)(&Xl[(m4 * 4 + 1) * 72 + kk4 * 4]) = w;
      w.x = (unsigned short)f2bf(v0.z); w.y = (unsigned short)f2bf(v1.z);
      w.z = (unsigned short)f2bf(v2.z); w.w = (unsigned short)f2bf(v3.z);
      *(ushort4*)(&Xl[(m4 * 4 + 2) * 72 + kk4 * 4]) = w;
      w.x = (unsigned short)f2bf(v0.w); w.y = (unsigned short)f2bf(v1.w);
      w.z = (unsigned short)f2bf(v2.w); w.w = (unsigned short)f2bf(v3.w);
      *(ushort4*)(&Xl[(m4 * 4 + 3) * 72 + kk4 * 4]) = w;
    }
    __syncthreads();
    s16x8 af[2][4], bfr[2][4];
#pragma unroll
    for (int h = 0; h < 2; ++h) {
#pragma unroll
      for (int i = 0; i < 4; ++i)
        af[h][i] = *(const s16x8*)(&Wl[(wv * 64 + i * 16 + lo) * 72 + h * 32 + quad * 8]);
#pragma unroll
      for (int j = 0; j < 4; ++j)
        bfr[h][j] = *(const s16x8*)(&Xl[(j * 16 + lo) * 72 + h * 32 + quad * 8]);
    }
#pragma unroll
    for (int h = 0; h < 2; ++h)
#pragma unroll
      for (int i = 0; i < 4; ++i)
#pragma unroll
        for (int j = 0; j < 4; ++j)
          acc[i][j] = __builtin_amdgcn_mfma_f32_16x16x32_bf16(af[h][i], bfr[h][j], acc[i][j], 0, 0, 0);
  }

  // ---------------- epilogue: combine with interp projection, store bf16 raw, stats
  float* P = (float*)Wl;                 // [32][260] f32, pad 256->260
  const float* Zb = Z + (size_t)b * SS * OC;
  unsigned short* rb = raw + (size_t)b * OC * MM;
  float ss[4][4] = {}, s2s[4][4] = {};
  __syncthreads();                       // Wl MFMA reads done, safe to reuse as P

#pragma unroll
  for (int h = 0; h < 2; ++h) {
    // build P[ml][o] = sum_j w_j * Z[idx_j][o] for m-half h (coalesced 1KB-row reads)
#pragma unroll 4
    for (int ml = 0; ml < 32; ++ml) {
      int mg = (h * 32 + ml) * 3;
      float p = mw3[mg + 0] * Zb[(size_t)mi3[mg + 0] * OC + tid]
              + mw3[mg + 1] * Zb[(size_t)mi3[mg + 1] * OC + tid]
              + mw3[mg + 2] * Zb[(size_t)mi3[mg + 2] * OC + tid];
      P[ml * 260 + tid] = p;
    }
    __syncthreads();
#pragma unroll
    for (int i = 0; i < 4; ++i)
#pragma unroll
      for (int jj = 0; jj < 2; ++jj) {
        int j = h * 2 + jj, ml = jj * 16 + lo;
        int o = wv * 64 + i * 16 + quad * 4;
        f32x4 p = *(const f32x4*)(&P[ml * 260 + o]);
        f32x4 v = acc[i][j] + p;
        unsigned short* dst = rb + (size_t)o * MM + m0 + j * 16 + lo;
#pragma unroll
        for (int r = 0; r < 4; ++r) {
          float vv = v[r];
          dst[(size_t)r * MM] = (unsigned short)f2bf(vv);
          ss[i][r] += vv; s2s[i][r] += vv * vv;
        }
      }
    __syncthreads();
  }

  // reduce stats across the 16 m-lanes of each quad (deterministic), write partials
#pragma unroll
  for (int i = 0; i < 4; ++i)
#pragma unroll
    for (int r = 0; r < 4; ++r) {
      float a = ss[i][r], q = s2s[i][r];
      for (int off = 1; off < 16; off <<= 1) { a += __shfl_xor(a, off); q += __shfl_xor(q, off); }
      ss[i][r] = a; s2s[i][r] = q;
    }
  if (lo == 0) {
#pragma unroll
    for (int i = 0; i < 4; ++i)
#pragma unroll
      for (int r = 0; r < 4; ++r) {
        int o = wv * 64 + i * 16 + quad * 4 + r;
        ps[(size_t)blk * OC + o]  = ss[i][r];
        ps2[(size_t)blk * OC + o] = s2s[i][r];
      }
  }
}

// ---------------------------------------------------------------- BN finalize -> fused scale/shift
// parallelized: 8 blocks x 32 channels
__global__ void k_finalize(const float* __restrict__ ps, const float* __restrict__ ps2,
                           const float* __restrict__ gamma, const float* __restrict__ beta,
                           float* __restrict__ sA, float* __restrict__ sB) {
  __shared__ float red[512];
  int blk = blockIdx.x;                    // 8 blocks
  int tid = threadIdx.x;
  int ch = tid & 31, sl = tid >> 5;        // 32 channels x 8 k-slices
  int o = blk * 32 + ch;
  float s = 0.f, s2 = 0.f;
#pragma unroll 4
  for (int j = 0; j < 64; ++j) {
    int k = sl * 64 + j;
    s  += ps[(size_t)k * OC + o];
    s2 += ps2[(size_t)k * OC + o];
  }
  red[sl * 32 + ch] = s;
  red[256 + sl * 32 + ch] = s2;
  __syncthreads();
  if (tid < 32) {
    float S = 0.f, S2 = 0.f;
#pragma unroll
    for (int t = 0; t < 8; ++t) { S += red[t * 32 + tid]; S2 += red[256 + t * 32 + tid]; }
    int oo = blk * 32 + tid;
    float mn = S / (float)(NB * MM);
    float vr = S2 / (float)(NB * MM) - mn * mn;
    float a  = rsqrtf(vr + BNEPS) * gamma[oo];
    sA[oo] = a;
    sB[oo] = beta[oo] - mn * a;
  }
}

// ---------------------------------------------------------------- BN apply + LeakyReLU
// reads bf16 raw (ushort8 = 16B/lane), writes f32 y (2x float4)
__global__ void k_norm(const unsigned short* __restrict__ raw, float* __restrict__ y,
                       const float* __restrict__ sA, const float* __restrict__ sB) {
  int i = blockIdx.x * 256 + threadIdx.x;   // ushort8 index; grid covers exactly
  int o = (i >> 9) & 255;                   // 512 ushort8 per (b,o) row
  float a = sA[o], be = sB[o];
  u16x8 v = ((const u16x8*)raw)[i];
  float out[8];
#pragma unroll
  for (int r = 0; r < 8; ++r) {
    union { unsigned u; float f; } c; c.u = ((unsigned)v[r]) << 16;
    float t = c.f * a + be;
    out[r] = t >= 0.f ? t : SLOPE * t;
  }
  float4* dst = (float4*)(y + (size_t)i * 8);
  dst[0] = make_float4(out[0], out[1], out[2], out[3]);
  dst[1] = make_float4(out[4], out[5], out[6], out[7]);
}

}  // namespace

extern "C" void kernel_launch(void* const* d_in, const int* in_sizes, int n_in,
                              void* d_out, int out_size, void* d_ws, size_t ws_size,
                              hipStream_t stream) {
  const float* dense = (const float*)d_in[0];
  const int*   didx  = (const int*)d_in[1];
  const float* sp    = (const float*)d_in[2];
  const int*   sidx  = (const int*)d_in[3];
  const float* pcd   = (const float*)d_in[4];
  const float* convw = (const float*)d_in[5];
  const float* gamma = (const float*)d_in[6];
  const float* beta  = (const float*)d_in[7];

  float* y = (float*)d_out;                       // [8][256][4096] normalized output
  float* outIdxF = y + (size_t)NB * OC * MM;      // output 1: dense_idx as float

  char* ws = (char*)d_ws;                         // ~27.4 MB of 256 MiB
  float*          Z    = (float*)(ws + OFF_Z);
  unsigned short* raw  = (unsigned short*)(ws + OFF_RAW);
  int*            idx3 = (int*)(ws + OFF_IDX3);
  float*          w3   = (float*)(ws + OFF_W3);
  short*          wbf  = (short*)(ws + OFF_WBF);
  float*          ps   = (float*)(ws + OFF_PS);
  float*          ps2  = (float*)(ws + OFF_PS2);
  float*          sA   = (float*)(ws + OFF_A);
  float*          sB   = (float*)(ws + OFF_B);

  k_knn     <<<NB * (MM / 64), 256, 0, stream>>>(didx, sidx, pcd, idx3, w3, outIdxF, convw, wbf);
  k_gemmZ   <<<NB * (SS / 32), 256, 0, stream>>>(sp, wbf, Z);
  k_gemmDC  <<<NB * (MM / 64), 256, 0, stream>>>(dense, Z, idx3, w3, wbf, raw, ps, ps2);
  k_finalize<<<8, 256, 0, stream>>>(ps, ps2, gamma, beta, sA, sB);
  k_norm    <<<(NB * OC * MM / 8) / 256, 256, 0, stream>>>(raw, y, sA, sB);
}